// Round 1
// baseline (273.098 us; speedup 1.0000x reference)
//
#include <hip/hip_runtime.h>

#define EPSF 1e-8f
#define NROWS 4096
#define NCOLS 8192
#define TPB 512           // threads per block (8 waves)
// each thread owns 4 float4s = 16 elements; 512*16 = 8192 = NCOLS

__global__ __launch_bounds__(TPB) void cecjs_main(const float* __restrict__ pred,
                                                  const float* __restrict__ gt,
                                                  double2* __restrict__ partial) {
    __shared__ float sred[16];
    __shared__ float bc0;   // broadcast: row max, then log(sumexp)
    __shared__ float bc1;   // broadcast: 1/sumexp

    const int row  = blockIdx.x;
    const int tid  = threadIdx.x;
    const int lane = tid & 63;
    const int wid  = tid >> 6;

    const float4* pr = (const float4*)(pred + (size_t)row * NCOLS);
    const float4* gr = (const float4*)(gt   + (size_t)row * NCOLS);

    // ---- phase 1: load pred into registers, row max ----
    float4 v[4];
    float mx = -3.4e38f;
    #pragma unroll
    for (int i = 0; i < 4; ++i) {
        v[i] = pr[tid + i * TPB];
        mx = fmaxf(mx, fmaxf(fmaxf(v[i].x, v[i].y), fmaxf(v[i].z, v[i].w)));
    }
    #pragma unroll
    for (int off = 32; off; off >>= 1) mx = fmaxf(mx, __shfl_down(mx, off, 64));
    if (lane == 0) sred[wid] = mx;
    __syncthreads();
    if (tid == 0) {
        float m = sred[0];
        #pragma unroll
        for (int i = 1; i < 8; ++i) m = fmaxf(m, sred[i]);
        bc0 = m;
    }
    __syncthreads();
    mx = bc0;

    // ---- phase 2: exp in registers, sum-exp ----
    float4 e[4];
    float s = 0.f;
    #pragma unroll
    for (int i = 0; i < 4; ++i) {
        e[i].x = __expf(v[i].x - mx);
        e[i].y = __expf(v[i].y - mx);
        e[i].z = __expf(v[i].z - mx);
        e[i].w = __expf(v[i].w - mx);
        s += (e[i].x + e[i].y) + (e[i].z + e[i].w);
    }
    #pragma unroll
    for (int off = 32; off; off >>= 1) s += __shfl_down(s, off, 64);
    if (lane == 0) sred[wid] = s;   // safe: prior reads of sred were before last barrier
    __syncthreads();
    if (tid == 0) {
        float t = 0.f;
        #pragma unroll
        for (int i = 0; i < 8; ++i) t += sred[i];
        bc0 = __logf(t);
        bc1 = 1.0f / t;
    }
    __syncthreads();
    const float logsum = bc0;
    const float invsum = bc1;

    // ---- phase 3: load gt, CE + weighted CJS contributions ----
    float ce = 0.f, cj = 0.f;
    #pragma unroll
    for (int i = 0; i < 4; ++i) {
        float4 g4 = gr[tid + i * TPB];
        const int c0 = (tid + i * TPB) * 4;
        #pragma unroll
        for (int k = 0; k < 4; ++k) {
            float x  = (&v[i].x)[k];
            float ev = (&e[i].x)[k];
            float g  = (&g4.x)[k];
            float lp = (x - mx) - logsum;       // log softmax
            float p  = ev * invsum;             // softmax
            ce += g * lp;
            float m    = 0.5f * (g + p + EPSF);
            float logm = __logf(m);
            float contrib = g * (__logf(g) - logm) + p * (lp - logm);
            cj += contrib * (float)(NCOLS - (c0 + k));
        }
    }
    #pragma unroll
    for (int off = 32; off; off >>= 1) {
        ce += __shfl_down(ce, off, 64);
        cj += __shfl_down(cj, off, 64);
    }
    if (lane == 0) { sred[wid * 2] = ce; sred[wid * 2 + 1] = cj; }
    __syncthreads();
    if (tid == 0) {
        double a = 0.0, b = 0.0;
        #pragma unroll
        for (int i = 0; i < 8; ++i) { a += (double)sred[2 * i]; b += (double)sred[2 * i + 1]; }
        partial[row] = make_double2(a, b);
    }
}

__global__ __launch_bounds__(512) void cecjs_final(const double2* __restrict__ partial,
                                                   float* __restrict__ out) {
    __shared__ double sce[8], scj[8];
    const int tid  = threadIdx.x;
    const int lane = tid & 63;
    const int wid  = tid >> 6;
    double ce = 0.0, cj = 0.0;
    for (int i = tid; i < NROWS; i += 512) {
        double2 d = partial[i];
        ce += d.x; cj += d.y;
    }
    #pragma unroll
    for (int off = 32; off; off >>= 1) {
        ce += __shfl_down(ce, off, 64);
        cj += __shfl_down(cj, off, 64);
    }
    if (lane == 0) { sce[wid] = ce; scj[wid] = cj; }
    __syncthreads();
    if (tid == 0) {
        double a = 0.0, b = 0.0;
        #pragma unroll
        for (int i = 0; i < 8; ++i) { a += sce[i]; b += scj[i]; }
        // loss = -S_ce/B + 0.5 * (0.5 * S_cjs / B) = (-S_ce + 0.25*S_cjs)/B
        out[0] = (float)((-a + 0.25 * b) / (double)NROWS);
    }
}

extern "C" void kernel_launch(void* const* d_in, const int* in_sizes, int n_in,
                              void* d_out, int out_size, void* d_ws, size_t ws_size,
                              hipStream_t stream) {
    const float* pred = (const float*)d_in[0];
    const float* gt   = (const float*)d_in[1];
    double2* partial  = (double2*)d_ws;      // needs 4096*16 = 64 KiB of scratch
    cecjs_main<<<NROWS, TPB, 0, stream>>>(pred, gt, partial);
    cecjs_final<<<1, 512, 0, stream>>>(partial, (float*)d_out);
}